// Round 1
// baseline (714.335 us; speedup 1.0000x reference)
//
#include <hip/hip_runtime.h>
#include <hip/hip_bf16.h>
#include <stdint.h>

#define N_NODES 128
#define T_DIM   4096
#define E_EDGES 72
#define IN_DIM  128
#define OUT_DIM 128
#define NRULE   3
#define TT      64      // T-tile rows per block
#define LDA     136     // padded LDS row stride in bf16 elems (+8 to break bank aliasing)

typedef float  f32x4 __attribute__((ext_vector_type(4)));
typedef short  s16x8 __attribute__((ext_vector_type(8)));

static __device__ __forceinline__ unsigned short f2bf(float f) {
    union { float f; unsigned int u; } v; v.f = f;
    unsigned int r = (v.u + 0x7FFFu + ((v.u >> 16) & 1u)) >> 16;  // RNE
    return (unsigned short)r;
}

// Convert weight[8][3][128][128] and loop_weight[128][128] (fp32) into bf16
// B-fragment order: wsB[mat][kstep][ntile][lane][j], mat 0..23 = et*3+r, 24 = loop.
// Fragment element j of lane L is B[k = kstep*32 + (L>>4)*8 + j][n = ntile*16 + (L&15)].
__global__ void conv_weights(const float* __restrict__ weight,
                             const float* __restrict__ loop_w,
                             unsigned short* __restrict__ wsB) {
    int g = blockIdx.x * blockDim.x + threadIdx.x;   // 25*2048 threads, 8 elems each
    if (g >= 25 * 2048) return;
    int mat  = g >> 11;
    int rem  = g & 2047;
    int kstep = rem >> 9;
    int nt    = (rem >> 6) & 7;
    int lane  = rem & 63;
    int quad = lane >> 4, l16 = lane & 15;
    const float* src = (mat < 24) ? (weight + (size_t)mat * IN_DIM * OUT_DIM) : loop_w;
    int col = nt * 16 + l16;
    int k0  = kstep * 32 + quad * 8;
    unsigned short tmp[8];
#pragma unroll
    for (int j = 0; j < 8; ++j)
        tmp[j] = f2bf(src[(size_t)(k0 + j) * OUT_DIM + col]);
    *(uint4*)(wsB + (size_t)g * 8) = *(const uint4*)tmp;   // 16B coalesced
}

__launch_bounds__(256)
__global__ void rgcn_main(const float* __restrict__ feat,
                          const float* __restrict__ tvg,
                          const float* __restrict__ h_bias,
                          const int*   __restrict__ src_idx,
                          const int*   __restrict__ dst_idx,
                          const int*   __restrict__ etypes,
                          const unsigned short* __restrict__ wsB,
                          float* __restrict__ out) {
    __shared__ unsigned short sA[TT * LDA];
    __shared__ float sTv[TT * 4];
    __shared__ int sSrc[E_EDGES], sDst[E_EDGES], sEt[E_EDGES];

    const int tid = threadIdx.x;
    const int n   = blockIdx.x & (N_NODES - 1);
    const int t0  = (blockIdx.x >> 7) * TT;

    if (tid < E_EDGES) {
        sSrc[tid] = src_idx[tid];
        sDst[tid] = dst_idx[tid];
        sEt[tid]  = etypes[tid];
    }

    // ---- stage self A tile (feat[n], rows t0..t0+63) fp32 -> bf16 LDS ----
    {
        const float* base = feat + ((size_t)n * T_DIM + t0) * IN_DIM;
        int r0 = tid >> 5;          // 0..7
        int c4 = tid & 31;          // float4 column
#pragma unroll
        for (int g = 0; g < 8; ++g) {
            int row = g * 8 + r0;
            float4 v = *(const float4*)(base + (size_t)row * IN_DIM + c4 * 4);
            unsigned short p[4] = { f2bf(v.x), f2bf(v.y), f2bf(v.z), f2bf(v.w) };
            *(uint2*)(sA + row * LDA + c4 * 4) = *(const uint2*)p;
        }
    }
    __syncthreads();

    const int wave = tid >> 6;
    const int lane = tid & 63;
    const int quad = lane >> 4, l16 = lane & 15;

    f32x4 acc[8];
#pragma unroll
    for (int i = 0; i < 8; ++i) acc[i] = f32x4{0.f, 0.f, 0.f, 0.f};

    // ---- self-loop GEMM: acc += A_self @ loop_weight (mat 24) ----
    {
        const unsigned short* bbase = wsB + 24 * 16384;
#pragma unroll
        for (int k = 0; k < 4; ++k) {
            s16x8 a = *(const s16x8*)(sA + (wave * 16 + l16) * LDA + k * 32 + quad * 8);
#pragma unroll
            for (int nt = 0; nt < 8; ++nt) {
                s16x8 b = *(const s16x8*)(bbase + k * 4096 + nt * 512 + lane * 8);
                acc[nt] = __builtin_amdgcn_mfma_f32_16x16x32_bf16(a, b, acc[nt], 0, 0, 0);
            }
        }
    }

    // ---- edges incident to this node ----
    for (int e = 0; e < E_EDGES; ++e) {
        if (sDst[e] != n) continue;           // block-uniform branch
        __syncthreads();                      // previous sA users done
        {   // stage A = feat[src[e]] tile
            const float* base = feat + ((size_t)sSrc[e] * T_DIM + t0) * IN_DIM;
            int r0 = tid >> 5, c4 = tid & 31;
#pragma unroll
            for (int g = 0; g < 8; ++g) {
                int row = g * 8 + r0;
                float4 v = *(const float4*)(base + (size_t)row * IN_DIM + c4 * 4);
                unsigned short p[4] = { f2bf(v.x), f2bf(v.y), f2bf(v.z), f2bf(v.w) };
                *(uint2*)(sA + row * LDA + c4 * 4) = *(const uint2*)p;
            }
        }
        if (tid < TT * NRULE) {               // stage tv tile: sTv[row][r]
            int row = tid / 3, r = tid % 3;
            sTv[row * 4 + r] = tvg[(size_t)e * (T_DIM * NRULE) + (size_t)t0 * NRULE + tid];
        }
        __syncthreads();

        s16x8 af[4];
#pragma unroll
        for (int k = 0; k < 4; ++k)
            af[k] = *(const s16x8*)(sA + (wave * 16 + l16) * LDA + k * 32 + quad * 8);

        const unsigned short* matbase = wsB + (size_t)sEt[e] * 3 * 16384;
#pragma unroll
        for (int r = 0; r < 3; ++r) {
            f32x4 pre[8];
#pragma unroll
            for (int i = 0; i < 8; ++i) pre[i] = f32x4{0.f, 0.f, 0.f, 0.f};
#pragma unroll
            for (int k = 0; k < 4; ++k) {
#pragma unroll
                for (int nt = 0; nt < 8; ++nt) {
                    s16x8 b = *(const s16x8*)(matbase + r * 16384 + k * 4096 + nt * 512 + lane * 8);
                    pre[nt] = __builtin_amdgcn_mfma_f32_16x16x32_bf16(af[k], b, pre[nt], 0, 0, 0);
                }
            }
            float tvv[4];
#pragma unroll
            for (int reg = 0; reg < 4; ++reg)
                tvv[reg] = sTv[(wave * 16 + quad * 4 + reg) * 4 + r];
#pragma unroll
            for (int nt = 0; nt < 8; ++nt)
#pragma unroll
                for (int reg = 0; reg < 4; ++reg)
                    acc[nt][reg] += tvv[reg] * pre[nt][reg];
        }
    }

    // ---- epilogue: bias + store (full overwrite, no zeroing needed) ----
#pragma unroll
    for (int nt = 0; nt < 8; ++nt) {
        float bias = h_bias[nt * 16 + l16];
#pragma unroll
        for (int reg = 0; reg < 4; ++reg) {
            int row = t0 + wave * 16 + quad * 4 + reg;
            out[((size_t)n * T_DIM + row) * OUT_DIM + nt * 16 + l16] = acc[nt][reg] + bias;
        }
    }
}

extern "C" void kernel_launch(void* const* d_in, const int* in_sizes, int n_in,
                              void* d_out, int out_size, void* d_ws, size_t ws_size,
                              hipStream_t stream) {
    const float* feat   = (const float*)d_in[0];
    const float* tv     = (const float*)d_in[1];
    const float* weight = (const float*)d_in[2];
    const float* loop_w = (const float*)d_in[3];
    const float* h_bias = (const float*)d_in[4];
    const int*   src    = (const int*)d_in[5];
    const int*   dst    = (const int*)d_in[6];
    const int*   et     = (const int*)d_in[7];
    float* out = (float*)d_out;

    unsigned short* wsB = (unsigned short*)d_ws;   // 25 * 16384 bf16 = 819200 B

    conv_weights<<<(25 * 2048 + 255) / 256, 256, 0, stream>>>(weight, loop_w, wsB);

    dim3 grid(N_NODES * (T_DIM / TT));             // 8192 blocks
    rgcn_main<<<grid, 256, 0, stream>>>(feat, tv, h_bias, src, dst, et, wsB, out);
}